// Round 7
// baseline (228.529 us; speedup 1.0000x reference)
//
#include <hip/hip_runtime.h>
#include <math.h>

#define NB_B 16
#define NB_S 4096
#define NB_D 64
#define NB_H 8

// LDS strides (in halfs) chosen so rows are 16B-aligned: 72*2=144=16*9,
// 136*2=272=16*17 -> every MFMA fragment is a single ds_read_b128.
#define KSTR 72
#define PSTR 136
#define VSTR 72

typedef _Float16 half_t;
typedef __attribute__((ext_vector_type(2))) _Float16 half2t;
typedef __attribute__((ext_vector_type(4))) _Float16 half4;
typedef __attribute__((ext_vector_type(8))) _Float16 half8;
typedef __attribute__((ext_vector_type(4))) float floatx4;
typedef __attribute__((ext_vector_type(2))) float float2v;

// ---------------- Kernel 0: precompute fp16 k-hat, v, f32 norm ----------------
// grid: B*S*16/256 blocks; 16 lanes per row. q = norm * khat (Q never stored).
__global__ __launch_bounds__(256) void prep_kernel(const float* __restrict__ qk,
                                                   const float* __restrict__ v,
                                                   half_t* __restrict__ khat,
                                                   half_t* __restrict__ vh,
                                                   float* __restrict__ norm) {
  int g = blockIdx.x * 256 + threadIdx.x;  // over B*S*16
  float4 qv = ((const float4*)qk)[g];
  float4 vv = ((const float4*)v)[g];
  float ss = qv.x * qv.x + qv.y * qv.y + qv.z * qv.z + qv.w * qv.w;
  for (int off = 1; off < 16; off <<= 1) ss += __shfl_xor(ss, off);
  float nr = fmaxf(sqrtf(ss), 1e-12f);
  float sc = 1.0f / nr;
  half4 hk = {(half_t)(qv.x * sc), (half_t)(qv.y * sc), (half_t)(qv.z * sc),
              (half_t)(qv.w * sc)};
  half4 hv = {(half_t)vv.x, (half_t)vv.y, (half_t)vv.z, (half_t)vv.w};
  ((half4*)khat)[g] = hk;
  ((half4*)vh)[g] = hv;
  if ((threadIdx.x & 15) == 0) norm[g >> 4] = nr;
}

// ---------------- Kernel 1: LSH hashing (buckets) ----------------
// Bit-faithful mimic of naive np.einsum float32 (keeps bucket decisions
// identical to the harness reference; summation order over f unchanged).
// v7 = R4's 4-token register blocking + R6's pk packing. R6 post-mortem:
// hash is LDS-PIPE-bound on the broadcast rot reads (64 ds_read_b128 per
// wave per fc ~= 768cy on the single per-CU LDS pipe vs 512cy pk-VALU);
// pk alone (R5->R6) didn't move time. reads-per-MAC ~ 1/(4*tok), so 4
// tokens/thread halves LDS demand per token (~20.5us/CU) while pk keeps
// VALU at ~14us -> predicted 30-40us. Both pieces individually proven
// bit-faithful on the harness (R4, R6). VGPR ~180 (acc2 128 + q 32).
// Keep __launch_bounds__(256, 1): a (256,2) bound capped VGPR at 128 and
// spilled acc (111MB/dispatch scratch, ~176us). DO NOT read rot via
// "uniform" global pointers (hipcc does not scalarize: 500us, R1). SINGLE
// loop nest, no fallback branch (old 2-path variant: 6.8GB spill, 3.1ms).
__global__ __launch_bounds__(256, 1) void hash_kernel(const float* __restrict__ qk,
                                                      const float* __restrict__ rot,
                                                      int* __restrict__ bkt) {
  __shared__ float rotS[64 * 32];  // [f][i]
  int tid = threadIdx.x;
  int blk = blockIdx.x;  // (b*8 + h)*4 + tile, grid = B*H*4 = 512
  int tile = blk & 3;
  int bh = blk >> 2;
  int h = bh & 7, b = bh >> 3;

  for (int i = tid; i < 2048; i += 256) {
    int f = i >> 5, ii = i & 31;
    rotS[i] = rot[(((size_t)b * 64 + f) * 8 + h) * 32 + ii];
  }
  __syncthreads();

  int t0 = (tile << 10) + tid;  // thread's tokens: t0 + 256*tok, tok=0..3
  const float* qb = qk + (((size_t)b << 12) << 6);

  float2v acc2[4][16];  // 16 pairs = 32 buckets per token
#pragma unroll
  for (int tok = 0; tok < 4; tok++)
#pragma unroll
    for (int i = 0; i < 16; i++) acc2[tok][i] = (float2v){0.f, 0.f};

#pragma unroll 1
  for (int fc = 0; fc < 8; fc++) {
    float q[4][8];
#pragma unroll
    for (int tok = 0; tok < 4; tok++) {
      const float4* qr =
          (const float4*)(qb + ((size_t)(t0 + (tok << 8)) << 6) + fc * 8);
      *(float4*)(q[tok]) = qr[0];
      *(float4*)(q[tok] + 4) = qr[1];
    }
#pragma unroll
    for (int fi = 0; fi < 8; fi++) {
#pragma unroll
      for (int i4 = 0; i4 < 8; i4++) {
        float4 wv = *(const float4*)(rotS + (fc * 8 + fi) * 32 + i4 * 4);
        float2v w0 = {wv.x, wv.y};
        float2v w1 = {wv.z, wv.w};
#pragma unroll
        for (int tok = 0; tok < 4; tok++) {
          float2v q2 = {q[tok][fi], q[tok][fi]};
          float2v p0, p1;
          asm("v_pk_mul_f32 %0, %2, %3\n\t"
              "v_pk_add_f32 %1, %1, %0"
              : "=&v"(p0), "+v"(acc2[tok][i4 * 2])
              : "v"(q2), "v"(w0));
          asm("v_pk_mul_f32 %0, %2, %3\n\t"
              "v_pk_add_f32 %1, %1, %0"
              : "=&v"(p1), "+v"(acc2[tok][i4 * 2 + 1])
              : "v"(q2), "v"(w1));
        }
      }
    }
  }

#pragma unroll
  for (int tok = 0; tok < 4; tok++) {
    float a[32];
#pragma unroll
    for (int p = 0; p < 16; p++) {
      a[2 * p] = acc2[tok][p].x;
      a[2 * p + 1] = acc2[tok][p].y;
    }
    float b1 = a[0];
    int i1 = 0;
#pragma unroll
    for (int i = 1; i < 32; i++)
      if (a[i] > b1) { b1 = a[i]; i1 = i; }
#pragma unroll
    for (int i = 0; i < 32; i++) {
      float x = -a[i];
      if (x > b1) { b1 = x; i1 = 32 + i; }
    }
    bkt[(((size_t)(b * 8 + h)) << 12) + t0 + (tok << 8)] = i1;
  }
}

// ---------------- Kernel 2: stable counting sort per (b,h) ----------------
__global__ __launch_bounds__(256) void sort_kernel(const int* __restrict__ bkt,
                                                   int* __restrict__ st) {
  __shared__ int lb[4096];
  __shared__ int hist[4096];  // [chunk(64)][bucket(64)]
  __shared__ int cumoff[64];
  int tid = threadIdx.x;
  int b = blockIdx.x >> 3, h = blockIdx.x & 7;
  const int* gb = bkt + (((size_t)(b * 8 + h)) << 12);
  for (int t = tid; t < 4096; t += 256) lb[t] = gb[t];
  for (int i = tid; i < 4096; i += 256) hist[i] = 0;
  __syncthreads();
  for (int t = tid; t < 4096; t += 256) atomicAdd(&hist[((t >> 6) << 6) | lb[t]], 1);
  __syncthreads();
  if (tid < 64) {
    int run = 0;
    for (int cc = 0; cc < 64; cc++) {
      int x = hist[(cc << 6) | tid];
      hist[(cc << 6) | tid] = run;
      run += x;
    }
    // exclusive prefix over buckets via wave-0 shfl scan
    int s = run;
    for (int off = 1; off < 64; off <<= 1) {
      int u = __shfl_up(s, off);
      if (tid >= off) s += u;
    }
    cumoff[tid] = s - run;
  }
  __syncthreads();
  int lane = tid & 63;
  for (int p = 0; p < 16; p++) {
    int t = (p << 8) + tid;  // each wave covers one aligned 64-token chunk
    int vb = lb[t];
    unsigned long long m = 0xFFFFFFFFFFFFFFFFull;
#pragma unroll
    for (int bit = 0; bit < 6; bit++) {
      unsigned long long bl = __ballot((vb >> bit) & 1);
      m &= ((vb >> bit) & 1) ? bl : ~bl;
    }
    int rank = __popcll(m & ((1ull << lane) - 1ull));
    int cpos = cumoff[vb] + hist[((t >> 6) << 6) | vb] + rank;
    st[(((size_t)(b * 8 + h)) << 12) + cpos] = t;
  }
}

// ---------------- Kernel 3: fused chunk kernel ----------------
// Per (b, round, chunk): QK^T (MFMA) -> per-round softmax -> P.V (MFMA),
// write normalized per-round output o_r (fp16) + lse_r. No atomics.
// grid: B*512 blocks, 256 threads = 4 waves.
// v5 = v3 exactly (74.1us measured). R6's direct-2B-store epilogue REGRESSED
// (74.1 -> 80.8us): 16 narrow global_store_short wave-instrs cost more than
// the 18 LDS ops + 2 barriers they replaced. Keep the O->LDS->b128 epilogue.
// v3: structural self-mask (st is a permutation: current-chunk self-match is
// key_idx==row_idx, nt==w uniform; look-back needs token compares only for
// the 8 c==0 chunks); exp2-domain softmax (MASK2 = -50000*log2e).
// v2: single-exp softmax, both V halves staged up front; the P-write ->
// pfr-read hop is intra-wave only (wave w writes/reads P rows [16w,16w+16)),
// no barrier there.
#define MASK2 -72134.76f
__global__ __launch_bounds__(256) void chunk_kernel(const half_t* __restrict__ khat,
                                                    const half_t* __restrict__ vh,
                                                    const float* __restrict__ norm,
                                                    const int* __restrict__ st,
                                                    half_t* __restrict__ oh,
                                                    float* __restrict__ lse) {
  __shared__ __align__(16) half_t Ks[128 * KSTR];  // K; later P (64 rows, PSTR)
  __shared__ __align__(16) half_t Vt0[64 * VSTR];  // V^T keys 0..63; later O
  __shared__ __align__(16) half_t Vt1[64 * VSTR];  // V^T keys 64..127
  __shared__ int tk[128];
  __shared__ float normS[64];
  int tid = threadIdx.x;
  int g = blockIdx.x & 511;
  int b = blockIdx.x >> 9;
  int h = g >> 6, c = g & 63;
  int gp = (g + 511) & 511;
  int hp = gp >> 6, cp = gp & 63;
  if (tid < 64) {
    tk[tid] = st[(((size_t)(b * 8 + h)) << 12) + (c << 6) + tid];
  } else if (tid < 128) {
    tk[tid] = st[(((size_t)(b * 8 + hp)) << 12) + (cp << 6) + (tid - 64)];
  }
  __syncthreads();
  if (tid < 64) normS[tid] = norm[(b << 12) + tk[tid]];
  // stage K (128 rows): single b128 load -> single b128 LDS store
  for (int idx = tid; idx < 1024; idx += 256) {
    int row = idx >> 3, fo = idx & 7;
    half8 val = *(const half8*)(khat + (((size_t)(b << 12) + tk[row]) << 6) + fo * 8);
    *(half8*)(Ks + row * KSTR + fo * 8) = val;
  }
  // stage BOTH V halves transposed (all gathers in flight together)
  {
    int kp = tid & 31, ch = tid >> 5;  // ch in 0..7
    half8 r0 = *(const half8*)(vh + (((size_t)(b << 12) + tk[2 * kp]) << 6) + ch * 8);
    half8 r1 = *(const half8*)(vh + (((size_t)(b << 12) + tk[2 * kp + 1]) << 6) + ch * 8);
    half8 r2 = *(const half8*)(vh + (((size_t)(b << 12) + tk[64 + 2 * kp]) << 6) + ch * 8);
    half8 r3 = *(const half8*)(vh + (((size_t)(b << 12) + tk[65 + 2 * kp]) << 6) + ch * 8);
#pragma unroll
    for (int j = 0; j < 8; j++) {
      half2t p0 = {r0[j], r1[j]};
      half2t p1 = {r2[j], r3[j]};
      *(half2t*)(Vt0 + (ch * 8 + j) * VSTR + 2 * kp) = p0;
      *(half2t*)(Vt1 + (ch * 8 + j) * VSTR + 2 * kp) = p1;
    }
  }
  __syncthreads();

  int lane = tid & 63, w = tid >> 6;
  int m = lane & 15, quad = lane >> 4;
  half8 afr[2];
#pragma unroll
  for (int ki = 0; ki < 2; ki++)
    afr[ki] = *(const half8*)(Ks + (w * 16 + m) * KSTR + ki * 32 + quad * 8);
  bool c0 = (c == 0);
  float scr[4];
#pragma unroll
  for (int r = 0; r < 4; r++) {
    int rr = w * 16 + quad * 4 + r;
    scr[r] = 0.18033688f * normS[rr];  // 0.125 * log2(e)
  }
  int ti[4] = {0, 0, 0, 0};
  if (c0) {
#pragma unroll
    for (int r = 0; r < 4; r++) ti[r] = tk[w * 16 + quad * 4 + r];
  }

  // QK^T dots (log2 domain), masked + scaled
  float d[8][4];
#pragma unroll
  for (int nt = 0; nt < 8; nt++) {
    floatx4 acc = {0.f, 0.f, 0.f, 0.f};
#pragma unroll
    for (int ki = 0; ki < 2; ki++) {
      half8 bfr = *(const half8*)(Ks + (nt * 16 + m) * KSTR + ki * 32 + quad * 8);
      acc = __builtin_amdgcn_mfma_f32_16x16x32_f16(afr[ki], bfr, acc, 0, 0, 0);
    }
    if (nt < 4) {
      // current-chunk keys: self-match iff key_idx == row_idx (permutation)
      if (nt == w) {
#pragma unroll
        for (int r = 0; r < 4; r++)
          d[nt][r] = (m == quad * 4 + r) ? MASK2 : acc[r] * scr[r];
      } else {
#pragma unroll
        for (int r = 0; r < 4; r++) d[nt][r] = acc[r] * scr[r];
      }
    } else {
      // look-back keys: same-round prev chunk (c>0) has distinct tokens
      if (c0) {
        int tj = tk[nt * 16 + m];
#pragma unroll
        for (int r = 0; r < 4; r++)
          d[nt][r] = (ti[r] == tj) ? MASK2 : acc[r] * scr[r];
      } else {
#pragma unroll
        for (int r = 0; r < 4; r++) d[nt][r] = acc[r] * scr[r];
      }
    }
  }

  // per-round row softmax (log2 domain): max, exp2 once in place, sum
  float mr4[4], lr4[4];
#pragma unroll
  for (int r = 0; r < 4; r++) {
    float mm = d[0][r];
#pragma unroll
    for (int nt = 1; nt < 8; nt++) mm = fmaxf(mm, d[nt][r]);
    for (int off = 1; off < 16; off <<= 1) mm = fmaxf(mm, __shfl_xor(mm, off));
    mr4[r] = mm;
  }
#pragma unroll
  for (int nt = 0; nt < 8; nt++)
#pragma unroll
    for (int r = 0; r < 4; r++)
      d[nt][r] = __builtin_amdgcn_exp2f(d[nt][r] - mr4[r]);
#pragma unroll
  for (int r = 0; r < 4; r++) {
    float ll = 0.f;
#pragma unroll
    for (int nt = 0; nt < 8; nt++) ll += d[nt][r];
    for (int off = 1; off < 16; off <<= 1) ll += __shfl_xor(ll, off);
    lr4[r] = ll;
    if (m == 0) {
      int rr = w * 16 + quad * 4 + r;
      lse[(((size_t)(b * 8 + h)) << 12) + tk[rr]] =
          0.69314718f * (mr4[r] + __builtin_amdgcn_logf(ll));
    }
  }
  __syncthreads();  // all waves done reading Ks as K

  // P' = exp2(d - m_r) fp16 into Ks region (stride PSTR); values already in d
  half_t* Ps = Ks;
#pragma unroll
  for (int nt = 0; nt < 8; nt++) {
#pragma unroll
    for (int r = 0; r < 4; r++) {
      Ps[(w * 16 + quad * 4 + r) * PSTR + nt * 16 + m] = (half_t)d[nt][r];
    }
  }
  // intra-wave RAW only (own 16 rows) -> compiler-ordered via lgkmcnt, no barrier

  half8 pfr[4];
#pragma unroll
  for (int kk = 0; kk < 4; kk++)
    pfr[kk] = *(const half8*)(Ps + (w * 16 + m) * PSTR + kk * 32 + quad * 8);

  floatx4 accO[4];
#pragma unroll
  for (int dt = 0; dt < 4; dt++) accO[dt] = (floatx4){0.f, 0.f, 0.f, 0.f};

  // PV over all 128 keys, contiguous MFMA cluster
#pragma unroll
  for (int dt = 0; dt < 4; dt++) {
#pragma unroll
    for (int kk = 0; kk < 2; kk++) {
      half8 bfr = *(const half8*)(Vt0 + (dt * 16 + m) * VSTR + kk * 32 + quad * 8);
      accO[dt] = __builtin_amdgcn_mfma_f32_16x16x32_f16(pfr[kk], bfr, accO[dt], 0, 0, 0);
    }
#pragma unroll
    for (int kk = 2; kk < 4; kk++) {
      half8 bfr = *(const half8*)(Vt1 + (dt * 16 + m) * VSTR + (kk - 2) * 32 + quad * 8);
      accO[dt] = __builtin_amdgcn_mfma_f32_16x16x32_f16(pfr[kk], bfr, accO[dt], 0, 0, 0);
    }
  }
  __syncthreads();  // all Vt0 reads done; reuse Vt0 for O

  // normalized O (fp16) -> LDS, then coalesced 16B row stores
  half_t* Ot = Vt0;
#pragma unroll
  for (int r = 0; r < 4; r++) {
    float inv = 1.0f / lr4[r];
#pragma unroll
    for (int dt = 0; dt < 4; dt++) {
      Ot[(w * 16 + quad * 4 + r) * VSTR + dt * 16 + m] = (half_t)(accO[dt][r] * inv);
    }
  }
  __syncthreads();
  for (int idx = tid; idx < 512; idx += 256) {
    int row = idx >> 3, fo = idx & 7;
    half8 val = *(const half8*)(Ot + row * VSTR + fo * 8);
    *(half8*)(oh + ((((size_t)(b * 8 + h)) << 12) + tk[row]) * 64 + fo * 8) = val;
  }
}

// ---------------- Kernel 4: combine rounds ----------------
// out[b,t,:] = sum_r exp(lse_r - lse_tot) * o_r[b,t,:]
// grid: B*S*8/256 blocks; thread = (token, 8-dim group)
__global__ __launch_bounds__(256) void combine_kernel(const half_t* __restrict__ oh,
                                                      const float* __restrict__ lse,
                                                      float* __restrict__ out) {
  int idx = blockIdx.x * 256 + threadIdx.x;  // over B*S*8
  int do8 = idx & 7;
  int ts = idx >> 3;  // b*4096 + t
  int b = ts >> 12, t = ts & 4095;
  size_t base = ((size_t)b << 15) + t;  // (b*8)<<12 + t
  float L[8];
  float m = -3.4e38f;
#pragma unroll
  for (int h = 0; h < 8; h++) {
    L[h] = lse[base + ((size_t)h << 12)];
    m = fmaxf(m, L[h]);
  }
  float s = 0.f;
#pragma unroll
  for (int h = 0; h < 8; h++) s += __expf(L[h] - m);
  float lt = m + __logf(s);
  float acc[8];
#pragma unroll
  for (int j = 0; j < 8; j++) acc[j] = 0.f;
#pragma unroll
  for (int h = 0; h < 8; h++) {
    float wgt = __expf(L[h] - lt);
    half8 o = *(const half8*)(oh + ((base + ((size_t)h << 12)) << 6) + do8 * 8);
#pragma unroll
    for (int j = 0; j < 8; j++) acc[j] += wgt * (float)o[j];
  }
  float* dst = out + ((((size_t)b << 12) + t) << 6) + do8 * 8;
  *(float4*)dst = (float4){acc[0], acc[1], acc[2], acc[3]};
  *(float4*)(dst + 4) = (float4){acc[4], acc[5], acc[6], acc[7]};
}

extern "C" void kernel_launch(void* const* d_in, const int* in_sizes, int n_in,
                              void* d_out, int out_size, void* d_ws, size_t ws_size,
                              hipStream_t stream) {
  const float* qk = (const float*)d_in[0];
  const float* v = (const float*)d_in[1];
  const float* rot = (const float*)d_in[2];
  float* out = (float*)d_out;

  int* bkt = (int*)d_ws;                            // 2MB
  int* stp = bkt + NB_B * NB_H * NB_S;              // 2MB
  float* lse = (float*)(stp + NB_B * NB_H * NB_S);  // 2MB
  float* norm = lse + NB_B * NB_H * NB_S;           // 256KB
  half_t* khat = (half_t*)(norm + NB_B * NB_S);     // 8MB
  half_t* vh = khat + (size_t)NB_B * NB_S * NB_D;   // 8MB
  half_t* oh = vh + (size_t)NB_B * NB_S * NB_D;     // B*H*S*D fp16 = 67MB

  prep_kernel<<<NB_B * NB_S * 16 / 256, 256, 0, stream>>>(qk, v, khat, vh, norm);
  hash_kernel<<<NB_B * NB_H * 4, 256, 0, stream>>>(qk, rot, bkt);
  sort_kernel<<<NB_B * NB_H, 256, 0, stream>>>(bkt, stp);
  chunk_kernel<<<NB_B * 512, 256, 0, stream>>>(khat, vh, norm, stp, oh, lse);
  combine_kernel<<<NB_B * NB_S * 8 / 256, 256, 0, stream>>>(oh, lse, out);
}

// Round 8
// 215.269 us; speedup vs baseline: 1.0616x; 1.0616x over previous
//
#include <hip/hip_runtime.h>
#include <math.h>

#define NB_B 16
#define NB_S 4096
#define NB_D 64
#define NB_H 8

// LDS strides (in halfs) chosen so rows are 16B-aligned: 72*2=144=16*9,
// 136*2=272=16*17 -> every MFMA fragment is a single ds_read_b128.
#define KSTR 72
#define PSTR 136
#define VSTR 72

typedef _Float16 half_t;
typedef __attribute__((ext_vector_type(2))) _Float16 half2t;
typedef __attribute__((ext_vector_type(4))) _Float16 half4;
typedef __attribute__((ext_vector_type(8))) _Float16 half8;
typedef __attribute__((ext_vector_type(4))) float floatx4;
typedef __attribute__((ext_vector_type(2))) float float2v;

// ---------------- Kernel 0: precompute fp16 k-hat, v, f32 norm ----------------
// grid: B*S*16/256 blocks; 16 lanes per row. q = norm * khat (Q never stored).
__global__ __launch_bounds__(256) void prep_kernel(const float* __restrict__ qk,
                                                   const float* __restrict__ v,
                                                   half_t* __restrict__ khat,
                                                   half_t* __restrict__ vh,
                                                   float* __restrict__ norm) {
  int g = blockIdx.x * 256 + threadIdx.x;  // over B*S*16
  float4 qv = ((const float4*)qk)[g];
  float4 vv = ((const float4*)v)[g];
  float ss = qv.x * qv.x + qv.y * qv.y + qv.z * qv.z + qv.w * qv.w;
  for (int off = 1; off < 16; off <<= 1) ss += __shfl_xor(ss, off);
  float nr = fmaxf(sqrtf(ss), 1e-12f);
  float sc = 1.0f / nr;
  half4 hk = {(half_t)(qv.x * sc), (half_t)(qv.y * sc), (half_t)(qv.z * sc),
              (half_t)(qv.w * sc)};
  half4 hv = {(half_t)vv.x, (half_t)vv.y, (half_t)vv.z, (half_t)vv.w};
  ((half4*)khat)[g] = hk;
  ((half4*)vh)[g] = hv;
  if ((threadIdx.x & 15) == 0) norm[g >> 4] = nr;
}

// ---------------- Kernel 1: LSH hashing (buckets) ----------------
// Bit-faithful mimic of naive np.einsum float32 (keeps bucket decisions
// identical to the harness reference; summation order over f unchanged).
// v8 = R6's proven 2-tok+pk body x TWO hash rounds per block (hh loop,
// structure proven bit-faithful in R1). Rationale: rest-of-pipeline was
// invariant (~135us) across ALL inner-loop variants (1/2/4-tok, scalar/pk)
// -> inner loop is not binding; the remaining hash cost is memory (qk
// re-fetched once per round) + latency. 2 rounds/block halves qk HBM fetch
// (134->67MB); the 2nd round's q reads hit L2 (block tile 128KB). rotS
// 16KB staged once. Grid 512 blocks -> 2 blocks/CU, 2 waves/SIMD, VGPR
// ~110 (NOT R7's 4-tok pk shape: acc2[4][16] in asm pair constraints
// regressed +20us from register-pair pressure).
// Keep __launch_bounds__(256, 1): a (256,2) bound capped VGPR at 128 and
// spilled acc (111MB/dispatch scratch, ~176us). DO NOT read rot via
// "uniform" global pointers (hipcc does not scalarize: 500us, R1). SINGLE
// loop nest per round, no fallback branch (old 2-path variant: 6.8GB
// spill, 3.1ms).
__global__ __launch_bounds__(256, 1) void hash_kernel(const float* __restrict__ qk,
                                                      const float* __restrict__ rot,
                                                      int* __restrict__ bkt) {
  __shared__ float rotS[2 * 2048];  // [hh][f*32+i]
  int tid = threadIdx.x;
  int blk = blockIdx.x;  // (b*4 + hp)*8 + tile, grid = B*4*8 = 512
  int tile = blk & 7;
  int bhp = blk >> 3;
  int hp = bhp & 3, b = bhp >> 2;

  for (int i = tid; i < 4096; i += 256) {
    int hh = i >> 11, r = i & 2047;
    int f = r >> 5, ii = r & 31;
    rotS[i] = rot[(((size_t)b * 64 + f) * 8 + (hp * 2 + hh)) * 32 + ii];
  }
  __syncthreads();

  int t0 = (tile << 9) + tid;  // thread's tokens: t0 + 256*tok, tok=0..1
  const float* qb = qk + (((size_t)b << 12) << 6);

#pragma unroll 1
  for (int hh = 0; hh < 2; hh++) {
    const float* rS = rotS + hh * 2048;
    int h = hp * 2 + hh;

    float2v acc2[2][16];  // 16 pairs = 32 buckets per token
#pragma unroll
    for (int tok = 0; tok < 2; tok++)
#pragma unroll
      for (int i = 0; i < 16; i++) acc2[tok][i] = (float2v){0.f, 0.f};

#pragma unroll 1
    for (int fc = 0; fc < 8; fc++) {
      float q[2][8];
#pragma unroll
      for (int tok = 0; tok < 2; tok++) {
        const float4* qr =
            (const float4*)(qb + ((size_t)(t0 + (tok << 8)) << 6) + fc * 8);
        *(float4*)(q[tok]) = qr[0];
        *(float4*)(q[tok] + 4) = qr[1];
      }
#pragma unroll
      for (int fi = 0; fi < 8; fi++) {
#pragma unroll
        for (int i4 = 0; i4 < 8; i4++) {
          float4 wv = *(const float4*)(rS + (fc * 8 + fi) * 32 + i4 * 4);
          float2v w0 = {wv.x, wv.y};
          float2v w1 = {wv.z, wv.w};
#pragma unroll
          for (int tok = 0; tok < 2; tok++) {
            float2v q2 = {q[tok][fi], q[tok][fi]};
            float2v p0, p1;
            asm("v_pk_mul_f32 %0, %2, %3\n\t"
                "v_pk_add_f32 %1, %1, %0"
                : "=&v"(p0), "+v"(acc2[tok][i4 * 2])
                : "v"(q2), "v"(w0));
            asm("v_pk_mul_f32 %0, %2, %3\n\t"
                "v_pk_add_f32 %1, %1, %0"
                : "=&v"(p1), "+v"(acc2[tok][i4 * 2 + 1])
                : "v"(q2), "v"(w1));
          }
        }
      }
    }

#pragma unroll
    for (int tok = 0; tok < 2; tok++) {
      float a[32];
#pragma unroll
      for (int p = 0; p < 16; p++) {
        a[2 * p] = acc2[tok][p].x;
        a[2 * p + 1] = acc2[tok][p].y;
      }
      float b1 = a[0];
      int i1 = 0;
#pragma unroll
      for (int i = 1; i < 32; i++)
        if (a[i] > b1) { b1 = a[i]; i1 = i; }
#pragma unroll
      for (int i = 0; i < 32; i++) {
        float x = -a[i];
        if (x > b1) { b1 = x; i1 = 32 + i; }
      }
      bkt[(((size_t)(b * 8 + h)) << 12) + t0 + (tok << 8)] = i1;
    }
  }
}

// ---------------- Kernel 2: stable counting sort per (b,h) ----------------
// v2: 1024 threads/block (was 256). The 128 blocks are latency-bound on a
// per-block critical path; 4x threads shrink the parallel phases 4x.
__global__ __launch_bounds__(1024) void sort_kernel(const int* __restrict__ bkt,
                                                    int* __restrict__ st) {
  __shared__ int lb[4096];
  __shared__ int hist[4096];  // [chunk(64)][bucket(64)]
  __shared__ int cumoff[64];
  int tid = threadIdx.x;
  int b = blockIdx.x >> 3, h = blockIdx.x & 7;
  const int* gb = bkt + (((size_t)(b * 8 + h)) << 12);
  for (int t = tid; t < 4096; t += 1024) lb[t] = gb[t];
  for (int i = tid; i < 4096; i += 1024) hist[i] = 0;
  __syncthreads();
  for (int t = tid; t < 4096; t += 1024) atomicAdd(&hist[((t >> 6) << 6) | lb[t]], 1);
  __syncthreads();
  if (tid < 64) {
    int run = 0;
    for (int cc = 0; cc < 64; cc++) {
      int x = hist[(cc << 6) | tid];
      hist[(cc << 6) | tid] = run;
      run += x;
    }
    // exclusive prefix over buckets via wave-0 shfl scan
    int s = run;
    for (int off = 1; off < 64; off <<= 1) {
      int u = __shfl_up(s, off);
      if (tid >= off) s += u;
    }
    cumoff[tid] = s - run;
  }
  __syncthreads();
  int lane = tid & 63;
  for (int p = 0; p < 4; p++) {
    int t = (p << 10) + tid;  // each wave covers one aligned 64-token chunk
    int vb = lb[t];
    unsigned long long m = 0xFFFFFFFFFFFFFFFFull;
#pragma unroll
    for (int bit = 0; bit < 6; bit++) {
      unsigned long long bl = __ballot((vb >> bit) & 1);
      m &= ((vb >> bit) & 1) ? bl : ~bl;
    }
    int rank = __popcll(m & ((1ull << lane) - 1ull));
    int cpos = cumoff[vb] + hist[((t >> 6) << 6) | vb] + rank;
    st[(((size_t)(b * 8 + h)) << 12) + cpos] = t;
  }
}

// ---------------- Kernel 3: fused chunk kernel ----------------
// Per (b, round, chunk): QK^T (MFMA) -> per-round softmax -> P.V (MFMA),
// write normalized per-round output o_r (fp16) + lse_r. No atomics.
// grid: B*512 blocks, 256 threads = 4 waves. Measured 73.4-74.1us.
// R6's direct-2B-store epilogue REGRESSED (74.1 -> 80.8us): keep the
// O->LDS->b128 epilogue. R5's VALU cut (55->46%) gave no time change and
// occupancy-insensitive (R0 47% == R5 38%) -> near structural limit for
// this 4-wave/128-key shape.
// v3: structural self-mask (st is a permutation: current-chunk self-match is
// key_idx==row_idx, nt==w uniform; look-back needs token compares only for
// the 8 c==0 chunks); exp2-domain softmax (MASK2 = -50000*log2e).
// v2: single-exp softmax, both V halves staged up front; the P-write ->
// pfr-read hop is intra-wave only (wave w writes/reads P rows [16w,16w+16)),
// no barrier there.
#define MASK2 -72134.76f
__global__ __launch_bounds__(256) void chunk_kernel(const half_t* __restrict__ khat,
                                                    const half_t* __restrict__ vh,
                                                    const float* __restrict__ norm,
                                                    const int* __restrict__ st,
                                                    half_t* __restrict__ oh,
                                                    float* __restrict__ lse) {
  __shared__ __align__(16) half_t Ks[128 * KSTR];  // K; later P (64 rows, PSTR)
  __shared__ __align__(16) half_t Vt0[64 * VSTR];  // V^T keys 0..63; later O
  __shared__ __align__(16) half_t Vt1[64 * VSTR];  // V^T keys 64..127
  __shared__ int tk[128];
  __shared__ float normS[64];
  int tid = threadIdx.x;
  int g = blockIdx.x & 511;
  int b = blockIdx.x >> 9;
  int h = g >> 6, c = g & 63;
  int gp = (g + 511) & 511;
  int hp = gp >> 6, cp = gp & 63;
  if (tid < 64) {
    tk[tid] = st[(((size_t)(b * 8 + h)) << 12) + (c << 6) + tid];
  } else if (tid < 128) {
    tk[tid] = st[(((size_t)(b * 8 + hp)) << 12) + (cp << 6) + (tid - 64)];
  }
  __syncthreads();
  if (tid < 64) normS[tid] = norm[(b << 12) + tk[tid]];
  // stage K (128 rows): single b128 load -> single b128 LDS store
  for (int idx = tid; idx < 1024; idx += 256) {
    int row = idx >> 3, fo = idx & 7;
    half8 val = *(const half8*)(khat + (((size_t)(b << 12) + tk[row]) << 6) + fo * 8);
    *(half8*)(Ks + row * KSTR + fo * 8) = val;
  }
  // stage BOTH V halves transposed (all gathers in flight together)
  {
    int kp = tid & 31, ch = tid >> 5;  // ch in 0..7
    half8 r0 = *(const half8*)(vh + (((size_t)(b << 12) + tk[2 * kp]) << 6) + ch * 8);
    half8 r1 = *(const half8*)(vh + (((size_t)(b << 12) + tk[2 * kp + 1]) << 6) + ch * 8);
    half8 r2 = *(const half8*)(vh + (((size_t)(b << 12) + tk[64 + 2 * kp]) << 6) + ch * 8);
    half8 r3 = *(const half8*)(vh + (((size_t)(b << 12) + tk[65 + 2 * kp]) << 6) + ch * 8);
#pragma unroll
    for (int j = 0; j < 8; j++) {
      half2t p0 = {r0[j], r1[j]};
      half2t p1 = {r2[j], r3[j]};
      *(half2t*)(Vt0 + (ch * 8 + j) * VSTR + 2 * kp) = p0;
      *(half2t*)(Vt1 + (ch * 8 + j) * VSTR + 2 * kp) = p1;
    }
  }
  __syncthreads();

  int lane = tid & 63, w = tid >> 6;
  int m = lane & 15, quad = lane >> 4;
  half8 afr[2];
#pragma unroll
  for (int ki = 0; ki < 2; ki++)
    afr[ki] = *(const half8*)(Ks + (w * 16 + m) * KSTR + ki * 32 + quad * 8);
  bool c0 = (c == 0);
  float scr[4];
#pragma unroll
  for (int r = 0; r < 4; r++) {
    int rr = w * 16 + quad * 4 + r;
    scr[r] = 0.18033688f * normS[rr];  // 0.125 * log2(e)
  }
  int ti[4] = {0, 0, 0, 0};
  if (c0) {
#pragma unroll
    for (int r = 0; r < 4; r++) ti[r] = tk[w * 16 + quad * 4 + r];
  }

  // QK^T dots (log2 domain), masked + scaled
  float d[8][4];
#pragma unroll
  for (int nt = 0; nt < 8; nt++) {
    floatx4 acc = {0.f, 0.f, 0.f, 0.f};
#pragma unroll
    for (int ki = 0; ki < 2; ki++) {
      half8 bfr = *(const half8*)(Ks + (nt * 16 + m) * KSTR + ki * 32 + quad * 8);
      acc = __builtin_amdgcn_mfma_f32_16x16x32_f16(afr[ki], bfr, acc, 0, 0, 0);
    }
    if (nt < 4) {
      // current-chunk keys: self-match iff key_idx == row_idx (permutation)
      if (nt == w) {
#pragma unroll
        for (int r = 0; r < 4; r++)
          d[nt][r] = (m == quad * 4 + r) ? MASK2 : acc[r] * scr[r];
      } else {
#pragma unroll
        for (int r = 0; r < 4; r++) d[nt][r] = acc[r] * scr[r];
      }
    } else {
      // look-back keys: same-round prev chunk (c>0) has distinct tokens
      if (c0) {
        int tj = tk[nt * 16 + m];
#pragma unroll
        for (int r = 0; r < 4; r++)
          d[nt][r] = (ti[r] == tj) ? MASK2 : acc[r] * scr[r];
      } else {
#pragma unroll
        for (int r = 0; r < 4; r++) d[nt][r] = acc[r] * scr[r];
      }
    }
  }

  // per-round row softmax (log2 domain): max, exp2 once in place, sum
  float mr4[4], lr4[4];
#pragma unroll
  for (int r = 0; r < 4; r++) {
    float mm = d[0][r];
#pragma unroll
    for (int nt = 1; nt < 8; nt++) mm = fmaxf(mm, d[nt][r]);
    for (int off = 1; off < 16; off <<= 1) mm = fmaxf(mm, __shfl_xor(mm, off));
    mr4[r] = mm;
  }
#pragma unroll
  for (int nt = 0; nt < 8; nt++)
#pragma unroll
    for (int r = 0; r < 4; r++)
      d[nt][r] = __builtin_amdgcn_exp2f(d[nt][r] - mr4[r]);
#pragma unroll
  for (int r = 0; r < 4; r++) {
    float ll = 0.f;
#pragma unroll
    for (int nt = 0; nt < 8; nt++) ll += d[nt][r];
    for (int off = 1; off < 16; off <<= 1) ll += __shfl_xor(ll, off);
    lr4[r] = ll;
    if (m == 0) {
      int rr = w * 16 + quad * 4 + r;
      lse[(((size_t)(b * 8 + h)) << 12) + tk[rr]] =
          0.69314718f * (mr4[r] + __builtin_amdgcn_logf(ll));
    }
  }
  __syncthreads();  // all waves done reading Ks as K

  // P' = exp2(d - m_r) fp16 into Ks region (stride PSTR); values already in d
  half_t* Ps = Ks;
#pragma unroll
  for (int nt = 0; nt < 8; nt++) {
#pragma unroll
    for (int r = 0; r < 4; r++) {
      Ps[(w * 16 + quad * 4 + r) * PSTR + nt * 16 + m] = (half_t)d[nt][r];
    }
  }
  // intra-wave RAW only (own 16 rows) -> compiler-ordered via lgkmcnt, no barrier

  half8 pfr[4];
#pragma unroll
  for (int kk = 0; kk < 4; kk++)
    pfr[kk] = *(const half8*)(Ps + (w * 16 + m) * PSTR + kk * 32 + quad * 8);

  floatx4 accO[4];
#pragma unroll
  for (int dt = 0; dt < 4; dt++) accO[dt] = (floatx4){0.f, 0.f, 0.f, 0.f};

  // PV over all 128 keys, contiguous MFMA cluster
#pragma unroll
  for (int dt = 0; dt < 4; dt++) {
#pragma unroll
    for (int kk = 0; kk < 2; kk++) {
      half8 bfr = *(const half8*)(Vt0 + (dt * 16 + m) * VSTR + kk * 32 + quad * 8);
      accO[dt] = __builtin_amdgcn_mfma_f32_16x16x32_f16(pfr[kk], bfr, accO[dt], 0, 0, 0);
    }
#pragma unroll
    for (int kk = 2; kk < 4; kk++) {
      half8 bfr = *(const half8*)(Vt1 + (dt * 16 + m) * VSTR + (kk - 2) * 32 + quad * 8);
      accO[dt] = __builtin_amdgcn_mfma_f32_16x16x32_f16(pfr[kk], bfr, accO[dt], 0, 0, 0);
    }
  }
  __syncthreads();  // all Vt0 reads done; reuse Vt0 for O

  // normalized O (fp16) -> LDS, then coalesced 16B row stores
  half_t* Ot = Vt0;
#pragma unroll
  for (int r = 0; r < 4; r++) {
    float inv = 1.0f / lr4[r];
#pragma unroll
    for (int dt = 0; dt < 4; dt++) {
      Ot[(w * 16 + quad * 4 + r) * VSTR + dt * 16 + m] = (half_t)(accO[dt][r] * inv);
    }
  }
  __syncthreads();
  for (int idx = tid; idx < 512; idx += 256) {
    int row = idx >> 3, fo = idx & 7;
    half8 val = *(const half8*)(Ot + row * VSTR + fo * 8);
    *(half8*)(oh + ((((size_t)(b * 8 + h)) << 12) + tk[row]) * 64 + fo * 8) = val;
  }
}

// ---------------- Kernel 4: combine rounds ----------------
// out[b,t,:] = sum_r exp(lse_r - lse_tot) * o_r[b,t,:]
// grid: B*S*8/256 blocks; thread = (token, 8-dim group)
__global__ __launch_bounds__(256) void combine_kernel(const half_t* __restrict__ oh,
                                                      const float* __restrict__ lse,
                                                      float* __restrict__ out) {
  int idx = blockIdx.x * 256 + threadIdx.x;  // over B*S*8
  int do8 = idx & 7;
  int ts = idx >> 3;  // b*4096 + t
  int b = ts >> 12, t = ts & 4095;
  size_t base = ((size_t)b << 15) + t;  // (b*8)<<12 + t
  float L[8];
  float m = -3.4e38f;
#pragma unroll
  for (int h = 0; h < 8; h++) {
    L[h] = lse[base + ((size_t)h << 12)];
    m = fmaxf(m, L[h]);
  }
  float s = 0.f;
#pragma unroll
  for (int h = 0; h < 8; h++) s += __expf(L[h] - m);
  float lt = m + __logf(s);
  float acc[8];
#pragma unroll
  for (int j = 0; j < 8; j++) acc[j] = 0.f;
#pragma unroll
  for (int h = 0; h < 8; h++) {
    float wgt = __expf(L[h] - lt);
    half8 o = *(const half8*)(oh + ((base + ((size_t)h << 12)) << 6) + do8 * 8);
#pragma unroll
    for (int j = 0; j < 8; j++) acc[j] += wgt * (float)o[j];
  }
  float* dst = out + ((((size_t)b << 12) + t) << 6) + do8 * 8;
  *(float4*)dst = (float4){acc[0], acc[1], acc[2], acc[3]};
  *(float4*)(dst + 4) = (float4){acc[4], acc[5], acc[6], acc[7]};
}

extern "C" void kernel_launch(void* const* d_in, const int* in_sizes, int n_in,
                              void* d_out, int out_size, void* d_ws, size_t ws_size,
                              hipStream_t stream) {
  const float* qk = (const float*)d_in[0];
  const float* v = (const float*)d_in[1];
  const float* rot = (const float*)d_in[2];
  float* out = (float*)d_out;

  int* bkt = (int*)d_ws;                            // 2MB
  int* stp = bkt + NB_B * NB_H * NB_S;              // 2MB
  float* lse = (float*)(stp + NB_B * NB_H * NB_S);  // 2MB
  float* norm = lse + NB_B * NB_H * NB_S;           // 256KB
  half_t* khat = (half_t*)(norm + NB_B * NB_S);     // 8MB
  half_t* vh = khat + (size_t)NB_B * NB_S * NB_D;   // 8MB
  half_t* oh = vh + (size_t)NB_B * NB_S * NB_D;     // B*H*S*D fp16 = 67MB

  prep_kernel<<<NB_B * NB_S * 16 / 256, 256, 0, stream>>>(qk, v, khat, vh, norm);
  hash_kernel<<<NB_B * 4 * 8, 256, 0, stream>>>(qk, rot, bkt);
  sort_kernel<<<NB_B * NB_H, 1024, 0, stream>>>(bkt, stp);
  chunk_kernel<<<NB_B * 512, 256, 0, stream>>>(khat, vh, norm, stp, oh, lse);
  combine_kernel<<<NB_B * NB_S * 8 / 256, 256, 0, stream>>>(oh, lse, out);
}

// Round 9
// 210.306 us; speedup vs baseline: 1.0867x; 1.0236x over previous
//
#include <hip/hip_runtime.h>
#include <math.h>

#define NB_B 16
#define NB_S 4096
#define NB_D 64
#define NB_H 8

// LDS strides (in halfs) chosen so rows are 16B-aligned: 72*2=144=16*9,
// 136*2=272=16*17 -> every MFMA fragment is a single ds_read_b128.
#define KSTR 72
#define PSTR 136
#define VSTR 72

typedef _Float16 half_t;
typedef __attribute__((ext_vector_type(2))) _Float16 half2t;
typedef __attribute__((ext_vector_type(4))) _Float16 half4;
typedef __attribute__((ext_vector_type(8))) _Float16 half8;
typedef __attribute__((ext_vector_type(4))) float floatx4;
typedef __attribute__((ext_vector_type(2))) float float2v;

// ---------------- Kernel 0: precompute fp16 k-hat, v, f32 norm ----------------
// grid: B*S*16/256 blocks; 16 lanes per row. q = norm * khat (Q never stored).
__global__ __launch_bounds__(256) void prep_kernel(const float* __restrict__ qk,
                                                   const float* __restrict__ v,
                                                   half_t* __restrict__ khat,
                                                   half_t* __restrict__ vh,
                                                   float* __restrict__ norm) {
  int g = blockIdx.x * 256 + threadIdx.x;  // over B*S*16
  float4 qv = ((const float4*)qk)[g];
  float4 vv = ((const float4*)v)[g];
  float ss = qv.x * qv.x + qv.y * qv.y + qv.z * qv.z + qv.w * qv.w;
  for (int off = 1; off < 16; off <<= 1) ss += __shfl_xor(ss, off);
  float nr = fmaxf(sqrtf(ss), 1e-12f);
  float sc = 1.0f / nr;
  half4 hk = {(half_t)(qv.x * sc), (half_t)(qv.y * sc), (half_t)(qv.z * sc),
              (half_t)(qv.w * sc)};
  half4 hv = {(half_t)vv.x, (half_t)vv.y, (half_t)vv.z, (half_t)vv.w};
  ((half4*)khat)[g] = hk;
  ((half4*)vh)[g] = hv;
  if ((threadIdx.x & 15) == 0) norm[g >> 4] = nr;
}

// ---------------- Kernel 1: LSH hashing (buckets) ----------------
// Bit-faithful mimic of naive np.einsum float32 (keeps bucket decisions
// identical to the harness reference; summation order over f unchanged).
// v8 (kept): R6's 2-tok+pk body x two hash rounds per block. NOTE: the whole
// hash lane is exhausted -- 1/2/4-tok, scalar/pk, 1/2-round variants all left
// total time invariant (rest-of-pipeline ~135-142us across R0-R8); qk is only
// 16.8MB (L2/L3-resident), so hash HBM ~17MB. Do not spend more rounds here.
// Keep __launch_bounds__(256, 1): a (256,2) bound capped VGPR at 128 and
// spilled acc (111MB/dispatch scratch, ~176us). DO NOT read rot via
// "uniform" global pointers (hipcc does not scalarize: 500us, R1). SINGLE
// loop nest per round, no fallback branch (old 2-path variant: 6.8GB spill,
// 3.1ms). R7's 4-tok+pk regressed (+20us, asm pair-constraint pressure).
__global__ __launch_bounds__(256, 1) void hash_kernel(const float* __restrict__ qk,
                                                      const float* __restrict__ rot,
                                                      int* __restrict__ bkt) {
  __shared__ float rotS[2 * 2048];  // [hh][f*32+i]
  int tid = threadIdx.x;
  int blk = blockIdx.x;  // (b*4 + hp)*8 + tile, grid = B*4*8 = 512
  int tile = blk & 7;
  int bhp = blk >> 3;
  int hp = bhp & 3, b = bhp >> 2;

  for (int i = tid; i < 4096; i += 256) {
    int hh = i >> 11, r = i & 2047;
    int f = r >> 5, ii = r & 31;
    rotS[i] = rot[(((size_t)b * 64 + f) * 8 + (hp * 2 + hh)) * 32 + ii];
  }
  __syncthreads();

  int t0 = (tile << 9) + tid;  // thread's tokens: t0 + 256*tok, tok=0..1
  const float* qb = qk + (((size_t)b << 12) << 6);

#pragma unroll 1
  for (int hh = 0; hh < 2; hh++) {
    const float* rS = rotS + hh * 2048;
    int h = hp * 2 + hh;

    float2v acc2[2][16];  // 16 pairs = 32 buckets per token
#pragma unroll
    for (int tok = 0; tok < 2; tok++)
#pragma unroll
      for (int i = 0; i < 16; i++) acc2[tok][i] = (float2v){0.f, 0.f};

#pragma unroll 1
    for (int fc = 0; fc < 8; fc++) {
      float q[2][8];
#pragma unroll
      for (int tok = 0; tok < 2; tok++) {
        const float4* qr =
            (const float4*)(qb + ((size_t)(t0 + (tok << 8)) << 6) + fc * 8);
        *(float4*)(q[tok]) = qr[0];
        *(float4*)(q[tok] + 4) = qr[1];
      }
#pragma unroll
      for (int fi = 0; fi < 8; fi++) {
#pragma unroll
        for (int i4 = 0; i4 < 8; i4++) {
          float4 wv = *(const float4*)(rS + (fc * 8 + fi) * 32 + i4 * 4);
          float2v w0 = {wv.x, wv.y};
          float2v w1 = {wv.z, wv.w};
#pragma unroll
          for (int tok = 0; tok < 2; tok++) {
            float2v q2 = {q[tok][fi], q[tok][fi]};
            float2v p0, p1;
            asm("v_pk_mul_f32 %0, %2, %3\n\t"
                "v_pk_add_f32 %1, %1, %0"
                : "=&v"(p0), "+v"(acc2[tok][i4 * 2])
                : "v"(q2), "v"(w0));
            asm("v_pk_mul_f32 %0, %2, %3\n\t"
                "v_pk_add_f32 %1, %1, %0"
                : "=&v"(p1), "+v"(acc2[tok][i4 * 2 + 1])
                : "v"(q2), "v"(w1));
          }
        }
      }
    }

#pragma unroll
    for (int tok = 0; tok < 2; tok++) {
      float a[32];
#pragma unroll
      for (int p = 0; p < 16; p++) {
        a[2 * p] = acc2[tok][p].x;
        a[2 * p + 1] = acc2[tok][p].y;
      }
      float b1 = a[0];
      int i1 = 0;
#pragma unroll
      for (int i = 1; i < 32; i++)
        if (a[i] > b1) { b1 = a[i]; i1 = i; }
#pragma unroll
      for (int i = 0; i < 32; i++) {
        float x = -a[i];
        if (x > b1) { b1 = x; i1 = 32 + i; }
      }
      bkt[(((size_t)(b * 8 + h)) << 12) + t0 + (tok << 8)] = i1;
    }
  }
}

// ---------------- Kernel 2: stable counting sort per (b,h) ----------------
// v2: 1024 threads/block (neutral vs 256, kept).
__global__ __launch_bounds__(1024) void sort_kernel(const int* __restrict__ bkt,
                                                    int* __restrict__ st) {
  __shared__ int lb[4096];
  __shared__ int hist[4096];  // [chunk(64)][bucket(64)]
  __shared__ int cumoff[64];
  int tid = threadIdx.x;
  int b = blockIdx.x >> 3, h = blockIdx.x & 7;
  const int* gb = bkt + (((size_t)(b * 8 + h)) << 12);
  for (int t = tid; t < 4096; t += 1024) lb[t] = gb[t];
  for (int i = tid; i < 4096; i += 1024) hist[i] = 0;
  __syncthreads();
  for (int t = tid; t < 4096; t += 1024) atomicAdd(&hist[((t >> 6) << 6) | lb[t]], 1);
  __syncthreads();
  if (tid < 64) {
    int run = 0;
    for (int cc = 0; cc < 64; cc++) {
      int x = hist[(cc << 6) | tid];
      hist[(cc << 6) | tid] = run;
      run += x;
    }
    // exclusive prefix over buckets via wave-0 shfl scan
    int s = run;
    for (int off = 1; off < 64; off <<= 1) {
      int u = __shfl_up(s, off);
      if (tid >= off) s += u;
    }
    cumoff[tid] = s - run;
  }
  __syncthreads();
  int lane = tid & 63;
  for (int p = 0; p < 4; p++) {
    int t = (p << 10) + tid;  // each wave covers one aligned 64-token chunk
    int vb = lb[t];
    unsigned long long m = 0xFFFFFFFFFFFFFFFFull;
#pragma unroll
    for (int bit = 0; bit < 6; bit++) {
      unsigned long long bl = __ballot((vb >> bit) & 1);
      m &= ((vb >> bit) & 1) ? bl : ~bl;
    }
    int rank = __popcll(m & ((1ull << lane) - 1ull));
    int cpos = cumoff[vb] + hist[((t >> 6) << 6) | vb] + rank;
    st[(((size_t)(b * 8 + h)) << 12) + cpos] = t;
  }
}

// ---------------- Kernel 3: fused chunk kernel ----------------
// Per (b, round, chunk): QK^T (MFMA) -> per-round softmax -> P.V (MFMA),
// write normalized per-round output o_r (fp16) + lse_r. No atomics.
// grid: B*512 blocks, 256 threads = 4 waves. Measured 73.4-74.1us.
// v6: XCD-aware block mapping (T1). OLD: blockIdx = b*512+g -> consecutive
// blocks (round-robin over 8 XCDs) share b -> every XCD L2 (4MB) must hold
// all 16 batches' khat+vh (16.8MB) -> thrash: FETCH 62MB vs ~17MB ideal,
// gathers at HBM latency. NEW: blockIdx = g*16+b -> XCD = b mod 8 -> each
// XCD serves 2 batches = 2.1MB, L2-fits; gathers become L2 hits. Pure index
// remap, no numerics change.
// R6's direct-2B-store epilogue REGRESSED (74.1 -> 80.8us): keep the
// O->LDS->b128 epilogue. R5's VALU cut (55->46%) gave no time change;
// occupancy-insensitive (R0 47% == R5 38%).
// v3: structural self-mask (st is a permutation: current-chunk self-match is
// key_idx==row_idx, nt==w uniform; look-back needs token compares only for
// the 8 c==0 chunks); exp2-domain softmax (MASK2 = -50000*log2e).
// v2: single-exp softmax, both V halves staged up front; the P-write ->
// pfr-read hop is intra-wave only (wave w writes/reads P rows [16w,16w+16)),
// no barrier there.
#define MASK2 -72134.76f
__global__ __launch_bounds__(256) void chunk_kernel(const half_t* __restrict__ khat,
                                                    const half_t* __restrict__ vh,
                                                    const float* __restrict__ norm,
                                                    const int* __restrict__ st,
                                                    half_t* __restrict__ oh,
                                                    float* __restrict__ lse) {
  __shared__ __align__(16) half_t Ks[128 * KSTR];  // K; later P (64 rows, PSTR)
  __shared__ __align__(16) half_t Vt0[64 * VSTR];  // V^T keys 0..63; later O
  __shared__ __align__(16) half_t Vt1[64 * VSTR];  // V^T keys 64..127
  __shared__ int tk[128];
  __shared__ float normS[64];
  int tid = threadIdx.x;
  // XCD swizzle: b in low 4 bits -> XCD = b & 7 -> per-XCD 2-batch L2 tile
  int b = blockIdx.x & 15;
  int g = blockIdx.x >> 4;
  int h = g >> 6, c = g & 63;
  int gp = (g + 511) & 511;
  int hp = gp >> 6, cp = gp & 63;
  if (tid < 64) {
    tk[tid] = st[(((size_t)(b * 8 + h)) << 12) + (c << 6) + tid];
  } else if (tid < 128) {
    tk[tid] = st[(((size_t)(b * 8 + hp)) << 12) + (cp << 6) + (tid - 64)];
  }
  __syncthreads();
  if (tid < 64) normS[tid] = norm[(b << 12) + tk[tid]];
  // stage K (128 rows): single b128 load -> single b128 LDS store
  for (int idx = tid; idx < 1024; idx += 256) {
    int row = idx >> 3, fo = idx & 7;
    half8 val = *(const half8*)(khat + (((size_t)(b << 12) + tk[row]) << 6) + fo * 8);
    *(half8*)(Ks + row * KSTR + fo * 8) = val;
  }
  // stage BOTH V halves transposed (all gathers in flight together)
  {
    int kp = tid & 31, ch = tid >> 5;  // ch in 0..7
    half8 r0 = *(const half8*)(vh + (((size_t)(b << 12) + tk[2 * kp]) << 6) + ch * 8);
    half8 r1 = *(const half8*)(vh + (((size_t)(b << 12) + tk[2 * kp + 1]) << 6) + ch * 8);
    half8 r2 = *(const half8*)(vh + (((size_t)(b << 12) + tk[64 + 2 * kp]) << 6) + ch * 8);
    half8 r3 = *(const half8*)(vh + (((size_t)(b << 12) + tk[65 + 2 * kp]) << 6) + ch * 8);
#pragma unroll
    for (int j = 0; j < 8; j++) {
      half2t p0 = {r0[j], r1[j]};
      half2t p1 = {r2[j], r3[j]};
      *(half2t*)(Vt0 + (ch * 8 + j) * VSTR + 2 * kp) = p0;
      *(half2t*)(Vt1 + (ch * 8 + j) * VSTR + 2 * kp) = p1;
    }
  }
  __syncthreads();

  int lane = tid & 63, w = tid >> 6;
  int m = lane & 15, quad = lane >> 4;
  half8 afr[2];
#pragma unroll
  for (int ki = 0; ki < 2; ki++)
    afr[ki] = *(const half8*)(Ks + (w * 16 + m) * KSTR + ki * 32 + quad * 8);
  bool c0 = (c == 0);
  float scr[4];
#pragma unroll
  for (int r = 0; r < 4; r++) {
    int rr = w * 16 + quad * 4 + r;
    scr[r] = 0.18033688f * normS[rr];  // 0.125 * log2(e)
  }
  int ti[4] = {0, 0, 0, 0};
  if (c0) {
#pragma unroll
    for (int r = 0; r < 4; r++) ti[r] = tk[w * 16 + quad * 4 + r];
  }

  // QK^T dots (log2 domain), masked + scaled
  float d[8][4];
#pragma unroll
  for (int nt = 0; nt < 8; nt++) {
    floatx4 acc = {0.f, 0.f, 0.f, 0.f};
#pragma unroll
    for (int ki = 0; ki < 2; ki++) {
      half8 bfr = *(const half8*)(Ks + (nt * 16 + m) * KSTR + ki * 32 + quad * 8);
      acc = __builtin_amdgcn_mfma_f32_16x16x32_f16(afr[ki], bfr, acc, 0, 0, 0);
    }
    if (nt < 4) {
      // current-chunk keys: self-match iff key_idx == row_idx (permutation)
      if (nt == w) {
#pragma unroll
        for (int r = 0; r < 4; r++)
          d[nt][r] = (m == quad * 4 + r) ? MASK2 : acc[r] * scr[r];
      } else {
#pragma unroll
        for (int r = 0; r < 4; r++) d[nt][r] = acc[r] * scr[r];
      }
    } else {
      // look-back keys: same-round prev chunk (c>0) has distinct tokens
      if (c0) {
        int tj = tk[nt * 16 + m];
#pragma unroll
        for (int r = 0; r < 4; r++)
          d[nt][r] = (ti[r] == tj) ? MASK2 : acc[r] * scr[r];
      } else {
#pragma unroll
        for (int r = 0; r < 4; r++) d[nt][r] = acc[r] * scr[r];
      }
    }
  }

  // per-round row softmax (log2 domain): max, exp2 once in place, sum
  float mr4[4], lr4[4];
#pragma unroll
  for (int r = 0; r < 4; r++) {
    float mm = d[0][r];
#pragma unroll
    for (int nt = 1; nt < 8; nt++) mm = fmaxf(mm, d[nt][r]);
    for (int off = 1; off < 16; off <<= 1) mm = fmaxf(mm, __shfl_xor(mm, off));
    mr4[r] = mm;
  }
#pragma unroll
  for (int nt = 0; nt < 8; nt++)
#pragma unroll
    for (int r = 0; r < 4; r++)
      d[nt][r] = __builtin_amdgcn_exp2f(d[nt][r] - mr4[r]);
#pragma unroll
  for (int r = 0; r < 4; r++) {
    float ll = 0.f;
#pragma unroll
    for (int nt = 0; nt < 8; nt++) ll += d[nt][r];
    for (int off = 1; off < 16; off <<= 1) ll += __shfl_xor(ll, off);
    lr4[r] = ll;
    if (m == 0) {
      int rr = w * 16 + quad * 4 + r;
      lse[(((size_t)(b * 8 + h)) << 12) + tk[rr]] =
          0.69314718f * (mr4[r] + __builtin_amdgcn_logf(ll));
    }
  }
  __syncthreads();  // all waves done reading Ks as K

  // P' = exp2(d - m_r) fp16 into Ks region (stride PSTR); values already in d
  half_t* Ps = Ks;
#pragma unroll
  for (int nt = 0; nt < 8; nt++) {
#pragma unroll
    for (int r = 0; r < 4; r++) {
      Ps[(w * 16 + quad * 4 + r) * PSTR + nt * 16 + m] = (half_t)d[nt][r];
    }
  }
  // intra-wave RAW only (own 16 rows) -> compiler-ordered via lgkmcnt, no barrier

  half8 pfr[4];
#pragma unroll
  for (int kk = 0; kk < 4; kk++)
    pfr[kk] = *(const half8*)(Ps + (w * 16 + m) * PSTR + kk * 32 + quad * 8);

  floatx4 accO[4];
#pragma unroll
  for (int dt = 0; dt < 4; dt++) accO[dt] = (floatx4){0.f, 0.f, 0.f, 0.f};

  // PV over all 128 keys, contiguous MFMA cluster
#pragma unroll
  for (int dt = 0; dt < 4; dt++) {
#pragma unroll
    for (int kk = 0; kk < 2; kk++) {
      half8 bfr = *(const half8*)(Vt0 + (dt * 16 + m) * VSTR + kk * 32 + quad * 8);
      accO[dt] = __builtin_amdgcn_mfma_f32_16x16x32_f16(pfr[kk], bfr, accO[dt], 0, 0, 0);
    }
#pragma unroll
    for (int kk = 2; kk < 4; kk++) {
      half8 bfr = *(const half8*)(Vt1 + (dt * 16 + m) * VSTR + (kk - 2) * 32 + quad * 8);
      accO[dt] = __builtin_amdgcn_mfma_f32_16x16x32_f16(pfr[kk], bfr, accO[dt], 0, 0, 0);
    }
  }
  __syncthreads();  // all Vt0 reads done; reuse Vt0 for O

  // normalized O (fp16) -> LDS, then coalesced 16B row stores
  half_t* Ot = Vt0;
#pragma unroll
  for (int r = 0; r < 4; r++) {
    float inv = 1.0f / lr4[r];
#pragma unroll
    for (int dt = 0; dt < 4; dt++) {
      Ot[(w * 16 + quad * 4 + r) * VSTR + dt * 16 + m] = (half_t)(accO[dt][r] * inv);
    }
  }
  __syncthreads();
  for (int idx = tid; idx < 512; idx += 256) {
    int row = idx >> 3, fo = idx & 7;
    half8 val = *(const half8*)(Ot + row * VSTR + fo * 8);
    *(half8*)(oh + ((((size_t)(b * 8 + h)) << 12) + tk[row]) * 64 + fo * 8) = val;
  }
}

// ---------------- Kernel 4: combine rounds ----------------
// out[b,t,:] = sum_r exp(lse_r - lse_tot) * o_r[b,t,:]
// grid: B*S*8/256 blocks; thread = (token, 8-dim group)
__global__ __launch_bounds__(256) void combine_kernel(const half_t* __restrict__ oh,
                                                      const float* __restrict__ lse,
                                                      float* __restrict__ out) {
  int idx = blockIdx.x * 256 + threadIdx.x;  // over B*S*8
  int do8 = idx & 7;
  int ts = idx >> 3;  // b*4096 + t
  int b = ts >> 12, t = ts & 4095;
  size_t base = ((size_t)b << 15) + t;  // (b*8)<<12 + t
  float L[8];
  float m = -3.4e38f;
#pragma unroll
  for (int h = 0; h < 8; h++) {
    L[h] = lse[base + ((size_t)h << 12)];
    m = fmaxf(m, L[h]);
  }
  float s = 0.f;
#pragma unroll
  for (int h = 0; h < 8; h++) s += __expf(L[h] - m);
  float lt = m + __logf(s);
  float acc[8];
#pragma unroll
  for (int j = 0; j < 8; j++) acc[j] = 0.f;
#pragma unroll
  for (int h = 0; h < 8; h++) {
    float wgt = __expf(L[h] - lt);
    half8 o = *(const half8*)(oh + ((base + ((size_t)h << 12)) << 6) + do8 * 8);
#pragma unroll
    for (int j = 0; j < 8; j++) acc[j] += wgt * (float)o[j];
  }
  float* dst = out + ((((size_t)b << 12) + t) << 6) + do8 * 8;
  *(float4*)dst = (float4){acc[0], acc[1], acc[2], acc[3]};
  *(float4*)(dst + 4) = (float4){acc[4], acc[5], acc[6], acc[7]};
}

extern "C" void kernel_launch(void* const* d_in, const int* in_sizes, int n_in,
                              void* d_out, int out_size, void* d_ws, size_t ws_size,
                              hipStream_t stream) {
  const float* qk = (const float*)d_in[0];
  const float* v = (const float*)d_in[1];
  const float* rot = (const float*)d_in[2];
  float* out = (float*)d_out;

  int* bkt = (int*)d_ws;                            // 2MB
  int* stp = bkt + NB_B * NB_H * NB_S;              // 2MB
  float* lse = (float*)(stp + NB_B * NB_H * NB_S);  // 2MB
  float* norm = lse + NB_B * NB_H * NB_S;           // 256KB
  half_t* khat = (half_t*)(norm + NB_B * NB_S);     // 8MB
  half_t* vh = khat + (size_t)NB_B * NB_S * NB_D;   // 8MB
  half_t* oh = vh + (size_t)NB_B * NB_S * NB_D;     // B*H*S*D fp16 = 67MB

  prep_kernel<<<NB_B * NB_S * 16 / 256, 256, 0, stream>>>(qk, v, khat, vh, norm);
  hash_kernel<<<NB_B * 4 * 8, 256, 0, stream>>>(qk, rot, bkt);
  sort_kernel<<<NB_B * NB_H, 1024, 0, stream>>>(bkt, stp);
  chunk_kernel<<<NB_B * 512, 256, 0, stream>>>(khat, vh, norm, stp, oh, lse);
  combine_kernel<<<NB_B * NB_S * 8 / 256, 256, 0, stream>>>(oh, lse, out);
}

// Round 10
// 204.574 us; speedup vs baseline: 1.1171x; 1.0280x over previous
//
#include <hip/hip_runtime.h>
#include <math.h>

#define NB_B 16
#define NB_S 4096
#define NB_D 64
#define NB_H 8

// LDS strides (in halfs) chosen so rows are 16B-aligned: 72*2=144=16*9,
// 136*2=272=16*17 -> every MFMA fragment is a single ds_read_b128.
#define KSTR 72
#define PSTR 136
#define VSTR 72

typedef _Float16 half_t;
typedef __attribute__((ext_vector_type(2))) _Float16 half2t;
typedef __attribute__((ext_vector_type(4))) _Float16 half4;
typedef __attribute__((ext_vector_type(8))) _Float16 half8;
typedef __attribute__((ext_vector_type(4))) float floatx4;
typedef __attribute__((ext_vector_type(2))) float float2v;

// ---------------- Kernel 0: precompute fp16 k-hat, v, f32 norm ----------------
// grid: B*S*16/256 blocks; 16 lanes per row. q = norm * khat (Q never stored).
__global__ __launch_bounds__(256) void prep_kernel(const float* __restrict__ qk,
                                                   const float* __restrict__ v,
                                                   half_t* __restrict__ khat,
                                                   half_t* __restrict__ vh,
                                                   float* __restrict__ norm) {
  int g = blockIdx.x * 256 + threadIdx.x;  // over B*S*16
  float4 qv = ((const float4*)qk)[g];
  float4 vv = ((const float4*)v)[g];
  float ss = qv.x * qv.x + qv.y * qv.y + qv.z * qv.z + qv.w * qv.w;
  for (int off = 1; off < 16; off <<= 1) ss += __shfl_xor(ss, off);
  float nr = fmaxf(sqrtf(ss), 1e-12f);
  float sc = 1.0f / nr;
  half4 hk = {(half_t)(qv.x * sc), (half_t)(qv.y * sc), (half_t)(qv.z * sc),
              (half_t)(qv.w * sc)};
  half4 hv = {(half_t)vv.x, (half_t)vv.y, (half_t)vv.z, (half_t)vv.w};
  ((half4*)khat)[g] = hk;
  ((half4*)vh)[g] = hv;
  if ((threadIdx.x & 15) == 0) norm[g >> 4] = nr;
}

// ---------------- Kernel 1: LSH hashing (buckets) ----------------
// Bit-faithful mimic of naive np.einsum float32 (keeps bucket decisions
// identical to the harness reference; per-h summation order over f unchanged:
// fc outer, fi inner, ascending).
// v9: BOTH hash rounds interleaved at the i4 level. Ledger across R0-R9:
// rest-of-pipeline invariant ~135-142us for every inner-loop variant
// (1/2/4-tok, scalar/pk, rounds outer-looped) -> hash ~100us vs ~14us pk-VALU
// floor. Common to all variants: q reloaded from global 8-16x/token with
// unroll-1 serial load->wait->compute chains; qk (16.8MB) misses the 4MB XCD
// L2 -> ~500-900cy exposed per fc step. This version keeps accA/accB (both
// rounds) live -> each fc's q-load (4 b128) is amortized over 1024cy of pk
// compute and load count halves. Static indexing only (rule #20).
// VGPR ~110-130. Keep __launch_bounds__(256, 1): a (256,2) bound capped VGPR
// at 128 and spilled acc (111MB/dispatch scratch). DO NOT read rot via
// "uniform" global pointers (hipcc does not scalarize: 500us, R1). SINGLE
// loop nest, no fallback branch (old 2-path variant: 6.8GB spill, 3.1ms).
// R7's 4-tok+pk regressed (asm pair-constraint pressure) -- stay at 2 tok.
__global__ __launch_bounds__(256, 1) void hash_kernel(const float* __restrict__ qk,
                                                      const float* __restrict__ rot,
                                                      int* __restrict__ bkt) {
  __shared__ float rotS[2 * 2048];  // [hh][f*32+i]
  int tid = threadIdx.x;
  int blk = blockIdx.x;  // (b*4 + hp)*8 + tile, grid = B*4*8 = 512
  int tile = blk & 7;
  int bhp = blk >> 3;
  int hp = bhp & 3, b = bhp >> 2;

  for (int i = tid; i < 4096; i += 256) {
    int hh = i >> 11, r = i & 2047;
    int f = r >> 5, ii = r & 31;
    rotS[i] = rot[(((size_t)b * 64 + f) * 8 + (hp * 2 + hh)) * 32 + ii];
  }
  __syncthreads();

  int t0 = (tile << 9) + tid;  // thread's tokens: t0 + 256*tok, tok=0..1
  const float* qb = qk + (((size_t)b << 12) << 6);

  float2v accA[2][16];  // round hh=0: 16 pairs = 32 buckets per token
  float2v accB[2][16];  // round hh=1
#pragma unroll
  for (int tok = 0; tok < 2; tok++)
#pragma unroll
    for (int i = 0; i < 16; i++) {
      accA[tok][i] = (float2v){0.f, 0.f};
      accB[tok][i] = (float2v){0.f, 0.f};
    }

#pragma unroll 1
  for (int fc = 0; fc < 8; fc++) {
    float q[2][8];
#pragma unroll
    for (int tok = 0; tok < 2; tok++) {
      const float4* qr =
          (const float4*)(qb + ((size_t)(t0 + (tok << 8)) << 6) + fc * 8);
      *(float4*)(q[tok]) = qr[0];
      *(float4*)(q[tok] + 4) = qr[1];
    }
#pragma unroll
    for (int fi = 0; fi < 8; fi++) {
#pragma unroll
      for (int i4 = 0; i4 < 8; i4++) {
        float4 wa = *(const float4*)(rotS + (fc * 8 + fi) * 32 + i4 * 4);
        float4 wb = *(const float4*)(rotS + 2048 + (fc * 8 + fi) * 32 + i4 * 4);
        float2v wa0 = {wa.x, wa.y}, wa1 = {wa.z, wa.w};
        float2v wb0 = {wb.x, wb.y}, wb1 = {wb.z, wb.w};
#pragma unroll
        for (int tok = 0; tok < 2; tok++) {
          float2v q2 = {q[tok][fi], q[tok][fi]};
          float2v p0, p1, p2, p3;
          asm("v_pk_mul_f32 %0, %2, %3\n\t"
              "v_pk_add_f32 %1, %1, %0"
              : "=&v"(p0), "+v"(accA[tok][i4 * 2])
              : "v"(q2), "v"(wa0));
          asm("v_pk_mul_f32 %0, %2, %3\n\t"
              "v_pk_add_f32 %1, %1, %0"
              : "=&v"(p1), "+v"(accA[tok][i4 * 2 + 1])
              : "v"(q2), "v"(wa1));
          asm("v_pk_mul_f32 %0, %2, %3\n\t"
              "v_pk_add_f32 %1, %1, %0"
              : "=&v"(p2), "+v"(accB[tok][i4 * 2])
              : "v"(q2), "v"(wb0));
          asm("v_pk_mul_f32 %0, %2, %3\n\t"
              "v_pk_add_f32 %1, %1, %0"
              : "=&v"(p3), "+v"(accB[tok][i4 * 2 + 1])
              : "v"(q2), "v"(wb1));
        }
      }
    }
  }

#define HASH_ARGMAX(ACC, H)                                              \
  {                                                                      \
    int h = (H);                                                         \
    _Pragma("unroll") for (int tok = 0; tok < 2; tok++) {                \
      float a[32];                                                       \
      _Pragma("unroll") for (int p = 0; p < 16; p++) {                   \
        a[2 * p] = ACC[tok][p].x;                                        \
        a[2 * p + 1] = ACC[tok][p].y;                                    \
      }                                                                  \
      float b1 = a[0];                                                   \
      int i1 = 0;                                                        \
      _Pragma("unroll") for (int i = 1; i < 32; i++) if (a[i] > b1) {    \
        b1 = a[i];                                                       \
        i1 = i;                                                          \
      }                                                                  \
      _Pragma("unroll") for (int i = 0; i < 32; i++) {                   \
        float x = -a[i];                                                 \
        if (x > b1) {                                                    \
          b1 = x;                                                        \
          i1 = 32 + i;                                                   \
        }                                                                \
      }                                                                  \
      bkt[(((size_t)(b * 8 + h)) << 12) + t0 + (tok << 8)] = i1;         \
    }                                                                    \
  }

  HASH_ARGMAX(accA, hp * 2)
  HASH_ARGMAX(accB, hp * 2 + 1)
#undef HASH_ARGMAX
}

// ---------------- Kernel 2: stable counting sort per (b,h) ----------------
// v2: 1024 threads/block (neutral vs 256, kept).
__global__ __launch_bounds__(1024) void sort_kernel(const int* __restrict__ bkt,
                                                    int* __restrict__ st) {
  __shared__ int lb[4096];
  __shared__ int hist[4096];  // [chunk(64)][bucket(64)]
  __shared__ int cumoff[64];
  int tid = threadIdx.x;
  int b = blockIdx.x >> 3, h = blockIdx.x & 7;
  const int* gb = bkt + (((size_t)(b * 8 + h)) << 12);
  for (int t = tid; t < 4096; t += 1024) lb[t] = gb[t];
  for (int i = tid; i < 4096; i += 1024) hist[i] = 0;
  __syncthreads();
  for (int t = tid; t < 4096; t += 1024) atomicAdd(&hist[((t >> 6) << 6) | lb[t]], 1);
  __syncthreads();
  if (tid < 64) {
    int run = 0;
    for (int cc = 0; cc < 64; cc++) {
      int x = hist[(cc << 6) | tid];
      hist[(cc << 6) | tid] = run;
      run += x;
    }
    // exclusive prefix over buckets via wave-0 shfl scan
    int s = run;
    for (int off = 1; off < 64; off <<= 1) {
      int u = __shfl_up(s, off);
      if (tid >= off) s += u;
    }
    cumoff[tid] = s - run;
  }
  __syncthreads();
  int lane = tid & 63;
  for (int p = 0; p < 4; p++) {
    int t = (p << 10) + tid;  // each wave covers one aligned 64-token chunk
    int vb = lb[t];
    unsigned long long m = 0xFFFFFFFFFFFFFFFFull;
#pragma unroll
    for (int bit = 0; bit < 6; bit++) {
      unsigned long long bl = __ballot((vb >> bit) & 1);
      m &= ((vb >> bit) & 1) ? bl : ~bl;
    }
    int rank = __popcll(m & ((1ull << lane) - 1ull));
    int cpos = cumoff[vb] + hist[((t >> 6) << 6) | vb] + rank;
    st[(((size_t)(b * 8 + h)) << 12) + cpos] = t;
  }
}

// ---------------- Kernel 3: fused chunk kernel ----------------
// Per (b, round, chunk): QK^T (MFMA) -> per-round softmax -> P.V (MFMA),
// write normalized per-round output o_r (fp16) + lse_r. No atomics.
// grid: B*512 blocks, 256 threads = 4 waves. Measured 71.7us (R9).
// v6: XCD-aware block mapping (T1): b in low 4 bits -> XCD = b&7 -> per-XCD
// 2-batch L2 tile (2.1MB fits 4MB L2). CONFIRMED on counters: FETCH 62->11MB.
// Time only -2us -> gathers were not the critical path; this kernel has now
// resisted 5 orthogonal probes (VALU cut, occupancy, direct stores, barrier
// cuts, L2 fix) at ~72us. Do not churn it further without a new counter
// signal. R6's direct-2B-store epilogue REGRESSED (74->81): keep the
// O->LDS->b128 epilogue.
// v3: structural self-mask (st is a permutation: current-chunk self-match is
// key_idx==row_idx, nt==w uniform; look-back needs token compares only for
// the 8 c==0 chunks); exp2-domain softmax (MASK2 = -50000*log2e).
// v2: single-exp softmax, both V halves staged up front; the P-write ->
// pfr-read hop is intra-wave only (wave w writes/reads P rows [16w,16w+16)),
// no barrier there.
#define MASK2 -72134.76f
__global__ __launch_bounds__(256) void chunk_kernel(const half_t* __restrict__ khat,
                                                    const half_t* __restrict__ vh,
                                                    const float* __restrict__ norm,
                                                    const int* __restrict__ st,
                                                    half_t* __restrict__ oh,
                                                    float* __restrict__ lse) {
  __shared__ __align__(16) half_t Ks[128 * KSTR];  // K; later P (64 rows, PSTR)
  __shared__ __align__(16) half_t Vt0[64 * VSTR];  // V^T keys 0..63; later O
  __shared__ __align__(16) half_t Vt1[64 * VSTR];  // V^T keys 64..127
  __shared__ int tk[128];
  __shared__ float normS[64];
  int tid = threadIdx.x;
  // XCD swizzle: b in low 4 bits -> XCD = b & 7 -> per-XCD 2-batch L2 tile
  int b = blockIdx.x & 15;
  int g = blockIdx.x >> 4;
  int h = g >> 6, c = g & 63;
  int gp = (g + 511) & 511;
  int hp = gp >> 6, cp = gp & 63;
  if (tid < 64) {
    tk[tid] = st[(((size_t)(b * 8 + h)) << 12) + (c << 6) + tid];
  } else if (tid < 128) {
    tk[tid] = st[(((size_t)(b * 8 + hp)) << 12) + (cp << 6) + (tid - 64)];
  }
  __syncthreads();
  if (tid < 64) normS[tid] = norm[(b << 12) + tk[tid]];
  // stage K (128 rows): single b128 load -> single b128 LDS store
  for (int idx = tid; idx < 1024; idx += 256) {
    int row = idx >> 3, fo = idx & 7;
    half8 val = *(const half8*)(khat + (((size_t)(b << 12) + tk[row]) << 6) + fo * 8);
    *(half8*)(Ks + row * KSTR + fo * 8) = val;
  }
  // stage BOTH V halves transposed (all gathers in flight together)
  {
    int kp = tid & 31, ch = tid >> 5;  // ch in 0..7
    half8 r0 = *(const half8*)(vh + (((size_t)(b << 12) + tk[2 * kp]) << 6) + ch * 8);
    half8 r1 = *(const half8*)(vh + (((size_t)(b << 12) + tk[2 * kp + 1]) << 6) + ch * 8);
    half8 r2 = *(const half8*)(vh + (((size_t)(b << 12) + tk[64 + 2 * kp]) << 6) + ch * 8);
    half8 r3 = *(const half8*)(vh + (((size_t)(b << 12) + tk[65 + 2 * kp]) << 6) + ch * 8);
#pragma unroll
    for (int j = 0; j < 8; j++) {
      half2t p0 = {r0[j], r1[j]};
      half2t p1 = {r2[j], r3[j]};
      *(half2t*)(Vt0 + (ch * 8 + j) * VSTR + 2 * kp) = p0;
      *(half2t*)(Vt1 + (ch * 8 + j) * VSTR + 2 * kp) = p1;
    }
  }
  __syncthreads();

  int lane = tid & 63, w = tid >> 6;
  int m = lane & 15, quad = lane >> 4;
  half8 afr[2];
#pragma unroll
  for (int ki = 0; ki < 2; ki++)
    afr[ki] = *(const half8*)(Ks + (w * 16 + m) * KSTR + ki * 32 + quad * 8);
  bool c0 = (c == 0);
  float scr[4];
#pragma unroll
  for (int r = 0; r < 4; r++) {
    int rr = w * 16 + quad * 4 + r;
    scr[r] = 0.18033688f * normS[rr];  // 0.125 * log2(e)
  }
  int ti[4] = {0, 0, 0, 0};
  if (c0) {
#pragma unroll
    for (int r = 0; r < 4; r++) ti[r] = tk[w * 16 + quad * 4 + r];
  }

  // QK^T dots (log2 domain), masked + scaled
  float d[8][4];
#pragma unroll
  for (int nt = 0; nt < 8; nt++) {
    floatx4 acc = {0.f, 0.f, 0.f, 0.f};
#pragma unroll
    for (int ki = 0; ki < 2; ki++) {
      half8 bfr = *(const half8*)(Ks + (nt * 16 + m) * KSTR + ki * 32 + quad * 8);
      acc = __builtin_amdgcn_mfma_f32_16x16x32_f16(afr[ki], bfr, acc, 0, 0, 0);
    }
    if (nt < 4) {
      // current-chunk keys: self-match iff key_idx == row_idx (permutation)
      if (nt == w) {
#pragma unroll
        for (int r = 0; r < 4; r++)
          d[nt][r] = (m == quad * 4 + r) ? MASK2 : acc[r] * scr[r];
      } else {
#pragma unroll
        for (int r = 0; r < 4; r++) d[nt][r] = acc[r] * scr[r];
      }
    } else {
      // look-back keys: same-round prev chunk (c>0) has distinct tokens
      if (c0) {
        int tj = tk[nt * 16 + m];
#pragma unroll
        for (int r = 0; r < 4; r++)
          d[nt][r] = (ti[r] == tj) ? MASK2 : acc[r] * scr[r];
      } else {
#pragma unroll
        for (int r = 0; r < 4; r++) d[nt][r] = acc[r] * scr[r];
      }
    }
  }

  // per-round row softmax (log2 domain): max, exp2 once in place, sum
  float mr4[4], lr4[4];
#pragma unroll
  for (int r = 0; r < 4; r++) {
    float mm = d[0][r];
#pragma unroll
    for (int nt = 1; nt < 8; nt++) mm = fmaxf(mm, d[nt][r]);
    for (int off = 1; off < 16; off <<= 1) mm = fmaxf(mm, __shfl_xor(mm, off));
    mr4[r] = mm;
  }
#pragma unroll
  for (int nt = 0; nt < 8; nt++)
#pragma unroll
    for (int r = 0; r < 4; r++)
      d[nt][r] = __builtin_amdgcn_exp2f(d[nt][r] - mr4[r]);
#pragma unroll
  for (int r = 0; r < 4; r++) {
    float ll = 0.f;
#pragma unroll
    for (int nt = 0; nt < 8; nt++) ll += d[nt][r];
    for (int off = 1; off < 16; off <<= 1) ll += __shfl_xor(ll, off);
    lr4[r] = ll;
    if (m == 0) {
      int rr = w * 16 + quad * 4 + r;
      lse[(((size_t)(b * 8 + h)) << 12) + tk[rr]] =
          0.69314718f * (mr4[r] + __builtin_amdgcn_logf(ll));
    }
  }
  __syncthreads();  // all waves done reading Ks as K

  // P' = exp2(d - m_r) fp16 into Ks region (stride PSTR); values already in d
  half_t* Ps = Ks;
#pragma unroll
  for (int nt = 0; nt < 8; nt++) {
#pragma unroll
    for (int r = 0; r < 4; r++) {
      Ps[(w * 16 + quad * 4 + r) * PSTR + nt * 16 + m] = (half_t)d[nt][r];
    }
  }
  // intra-wave RAW only (own 16 rows) -> compiler-ordered via lgkmcnt, no barrier

  half8 pfr[4];
#pragma unroll
  for (int kk = 0; kk < 4; kk++)
    pfr[kk] = *(const half8*)(Ps + (w * 16 + m) * PSTR + kk * 32 + quad * 8);

  floatx4 accO[4];
#pragma unroll
  for (int dt = 0; dt < 4; dt++) accO[dt] = (floatx4){0.f, 0.f, 0.f, 0.f};

  // PV over all 128 keys, contiguous MFMA cluster
#pragma unroll
  for (int dt = 0; dt < 4; dt++) {
#pragma unroll
    for (int kk = 0; kk < 2; kk++) {
      half8 bfr = *(const half8*)(Vt0 + (dt * 16 + m) * VSTR + kk * 32 + quad * 8);
      accO[dt] = __builtin_amdgcn_mfma_f32_16x16x32_f16(pfr[kk], bfr, accO[dt], 0, 0, 0);
    }
#pragma unroll
    for (int kk = 2; kk < 4; kk++) {
      half8 bfr = *(const half8*)(Vt1 + (dt * 16 + m) * VSTR + (kk - 2) * 32 + quad * 8);
      accO[dt] = __builtin_amdgcn_mfma_f32_16x16x32_f16(pfr[kk], bfr, accO[dt], 0, 0, 0);
    }
  }
  __syncthreads();  // all Vt0 reads done; reuse Vt0 for O

  // normalized O (fp16) -> LDS, then coalesced 16B row stores
  half_t* Ot = Vt0;
#pragma unroll
  for (int r = 0; r < 4; r++) {
    float inv = 1.0f / lr4[r];
#pragma unroll
    for (int dt = 0; dt < 4; dt++) {
      Ot[(w * 16 + quad * 4 + r) * VSTR + dt * 16 + m] = (half_t)(accO[dt][r] * inv);
    }
  }
  __syncthreads();
  for (int idx = tid; idx < 512; idx += 256) {
    int row = idx >> 3, fo = idx & 7;
    half8 val = *(const half8*)(Ot + row * VSTR + fo * 8);
    *(half8*)(oh + ((((size_t)(b * 8 + h)) << 12) + tk[row]) * 64 + fo * 8) = val;
  }
}

// ---------------- Kernel 4: combine rounds ----------------
// out[b,t,:] = sum_r exp(lse_r - lse_tot) * o_r[b,t,:]
// grid: B*S*8/256 blocks; thread = (token, 8-dim group)
__global__ __launch_bounds__(256) void combine_kernel(const half_t* __restrict__ oh,
                                                      const float* __restrict__ lse,
                                                      float* __restrict__ out) {
  int idx = blockIdx.x * 256 + threadIdx.x;  // over B*S*8
  int do8 = idx & 7;
  int ts = idx >> 3;  // b*4096 + t
  int b = ts >> 12, t = ts & 4095;
  size_t base = ((size_t)b << 15) + t;  // (b*8)<<12 + t
  float L[8];
  float m = -3.4e38f;
#pragma unroll
  for (int h = 0; h < 8; h++) {
    L[h] = lse[base + ((size_t)h << 12)];
    m = fmaxf(m, L[h]);
  }
  float s = 0.f;
#pragma unroll
  for (int h = 0; h < 8; h++) s += __expf(L[h] - m);
  float lt = m + __logf(s);
  float acc[8];
#pragma unroll
  for (int j = 0; j < 8; j++) acc[j] = 0.f;
#pragma unroll
  for (int h = 0; h < 8; h++) {
    float wgt = __expf(L[h] - lt);
    half8 o = *(const half8*)(oh + ((base + ((size_t)h << 12)) << 6) + do8 * 8);
#pragma unroll
    for (int j = 0; j < 8; j++) acc[j] += wgt * (float)o[j];
  }
  float* dst = out + ((((size_t)b << 12) + t) << 6) + do8 * 8;
  *(float4*)dst = (float4){acc[0], acc[1], acc[2], acc[3]};
  *(float4*)(dst + 4) = (float4){acc[4], acc[5], acc[6], acc[7]};
}

extern "C" void kernel_launch(void* const* d_in, const int* in_sizes, int n_in,
                              void* d_out, int out_size, void* d_ws, size_t ws_size,
                              hipStream_t stream) {
  const float* qk = (const float*)d_in[0];
  const float* v = (const float*)d_in[1];
  const float* rot = (const float*)d_in[2];
  float* out = (float*)d_out;

  int* bkt = (int*)d_ws;                            // 2MB
  int* stp = bkt + NB_B * NB_H * NB_S;              // 2MB
  float* lse = (float*)(stp + NB_B * NB_H * NB_S);  // 2MB
  float* norm = lse + NB_B * NB_H * NB_S;           // 256KB
  half_t* khat = (half_t*)(norm + NB_B * NB_S);     // 8MB
  half_t* vh = khat + (size_t)NB_B * NB_S * NB_D;   // 8MB
  half_t* oh = vh + (size_t)NB_B * NB_S * NB_D;     // B*H*S*D fp16 = 67MB

  prep_kernel<<<NB_B * NB_S * 16 / 256, 256, 0, stream>>>(qk, v, khat, vh, norm);
  hash_kernel<<<NB_B * 4 * 8, 256, 0, stream>>>(qk, rot, bkt);
  sort_kernel<<<NB_B * NB_H, 1024, 0, stream>>>(bkt, stp);
  chunk_kernel<<<NB_B * 512, 256, 0, stream>>>(khat, vh, norm, stp, oh, lse);
  combine_kernel<<<NB_B * NB_S * 8 / 256, 256, 0, stream>>>(oh, lse, out);
}